// Round 2
// baseline (98.878 us; speedup 1.0000x reference)
//
#include <hip/hip_runtime.h>
#include <cstdint>

#define T_STEPS 2048
#define NFEAT   2048
#define A_POS 0.05f
#define A_NEG 0.05f
#define LR    0.01f
#define DECAY 0.60653065971263342f   // exp(-1/2), tau_pos == tau_neg == 2
#define SPLITK 4
#define KSLAB  (T_STEPS / SPLITK)    // 512

typedef unsigned short u16;
typedef short short8 __attribute__((ext_vector_type(8)));
typedef float f32x4 __attribute__((ext_vector_type(4)));

__device__ __forceinline__ uint32_t f2bf(float f) {
  uint32_t u = __float_as_uint(f);
  return (u + 0x7FFFu + ((u >> 16) & 1u)) >> 16;   // RNE, finite values only
}
__device__ __forceinline__ uint32_t packbf2(float lo, float hi) {
  return f2bf(lo) | (f2bf(hi) << 16);
}

// ---------------------------------------------------------------------------
// Prep kernel (fused, block-range dispatch):
//  blocks [0,256):     scan -> kinT[j][t] bf16    (exponential STDP scans)
//  blocks [256,1280):  transpose -> outT[i][t] bf16
//  blocks [1280,1792): copy W -> C (so GEMM can atomicAdd into C)
// ---------------------------------------------------------------------------
#define TC   64
#define HALO 64
__global__ __launch_bounds__(256) void prep_kernel(
    const float* __restrict__ in, const float* __restrict__ outspk,
    const float* __restrict__ W, u16* __restrict__ kinT,
    u16* __restrict__ outT, float* __restrict__ C) {
  const int bx = blockIdx.x;
  const int tid = threadIdx.x;

  if (bx < 256) {
    // ---- scan role ----
    const int j  = (bx & 7) * 256 + tid;
    const int t0 = (bx >> 3) * TC;
    const float d = DECAY;

    float kv[TC];
    float f = 0.f;
    int tb = t0 - HALO; if (tb < 0) tb = 0;
    for (int t = tb; t < t0; ++t) f = d * (f + in[(size_t)t * NFEAT + j]);
#pragma unroll
    for (int u = 0; u < TC; ++u) {
      kv[u] = f;                                   // F[t0+u] (excludes in[t0+u])
      f = d * (f + in[(size_t)(t0 + u) * NFEAT + j]);
    }

    float b = 0.f;
    int te = t0 + TC - 1 + HALO; if (te > T_STEPS - 1) te = T_STEPS - 1;
    for (int t = te; t >= t0 + TC; --t) b = in[(size_t)t * NFEAT + j] + d * b;
#pragma unroll
    for (int u = TC - 1; u >= 0; --u) {
      b = in[(size_t)(t0 + u) * NFEAT + j] + d * b;  // B[t0+u] (includes t)
      kv[u] = A_POS * kv[u] - A_NEG * b;
    }

    uint4* dst = (uint4*)&kinT[(size_t)j * T_STEPS + t0];
#pragma unroll
    for (int g = 0; g < TC / 8; ++g) {
      uint4 w;
      w.x = packbf2(kv[8 * g + 0], kv[8 * g + 1]);
      w.y = packbf2(kv[8 * g + 2], kv[8 * g + 3]);
      w.z = packbf2(kv[8 * g + 4], kv[8 * g + 5]);
      w.w = packbf2(kv[8 * g + 6], kv[8 * g + 7]);
      dst[g] = w;
    }
  } else if (bx < 1280) {
    // ---- transpose role ----
    __shared__ float tile[64][65];
    const int b  = bx - 256;
    const int t0 = (b & 31) * 64;
    const int i0 = (b >> 5) * 64;
#pragma unroll
    for (int p = 0; p < 16; ++p) {
      int idx = tid + p * 256;
      int r = idx >> 6, c = idx & 63;
      tile[r][c] = outspk[(size_t)(t0 + r) * NFEAT + i0 + c];
    }
    __syncthreads();
#pragma unroll
    for (int p = 0; p < 8; ++p) {
      int idx = tid + p * 256;
      int pr = idx >> 5, pc = idx & 31;
      uint32_t w = packbf2(tile[2 * pc][pr], tile[2 * pc + 1][pr]);
      ((uint32_t*)outT)[(size_t)(i0 + pr) * (T_STEPS / 2) + (t0 >> 1) + pc] = w;
    }
  } else {
    // ---- W -> C copy role (512 blocks, float4 grid-stride) ----
    const int b = bx - 1280;
    const float4* s = (const float4*)W;
    float4* d4 = (float4*)C;
    const int total = NFEAT * NFEAT / 4;
    for (int idx = b * 256 + tid; idx < total; idx += 512 * 256) d4[idx] = s[idx];
  }
}

// ---------------------------------------------------------------------------
// GEMM (split-K=4): C[i][j] += LR * sum_{k in slab} A[i][k]*B[j][k]  (atomic)
// A = outT, B = kinT, both bf16 K-contiguous. 128x128 tile, BK=32, 4 waves.
// ---------------------------------------------------------------------------
__global__ __launch_bounds__(256) void stdp_gemm_kernel(
    const u16* __restrict__ A, const u16* __restrict__ B,
    float* __restrict__ C) {
  __shared__ u16 ldsA[2][128 * 32];
  __shared__ u16 ldsB[2][128 * 32];
  const int tid = threadIdx.x;
  const int lane = tid & 63, wave = tid >> 6;
  const int wm = wave >> 1, wn = wave & 1;
  const int i0 = blockIdx.y * 128, j0 = blockIdx.x * 128;
  const int kbase = blockIdx.z * KSLAB;
  const int lr = lane & 15, lk = lane >> 4;

  f32x4 acc[4][4];
#pragma unroll
  for (int m = 0; m < 4; ++m)
#pragma unroll
    for (int n = 0; n < 4; ++n) acc[m][n] = (f32x4){0.f, 0.f, 0.f, 0.f};

  auto stage = [&](int buf, int kt) {
    const int k0 = kbase + kt * 32;
#pragma unroll
    for (int h = 0; h < 2; ++h) {
      int chunk = h * 256 + tid;
      int r = chunk >> 2, c = chunk & 3;
      __builtin_amdgcn_global_load_lds(
          (const __attribute__((address_space(1))) void*)(A + (size_t)(i0 + r) * T_STEPS + k0 + c * 8),
          (__attribute__((address_space(3))) void*)((char*)&ldsA[buf][0] + (h * 256 + wave * 64) * 16),
          16, 0, 0);
      __builtin_amdgcn_global_load_lds(
          (const __attribute__((address_space(1))) void*)(B + (size_t)(j0 + r) * T_STEPS + k0 + c * 8),
          (__attribute__((address_space(3))) void*)((char*)&ldsB[buf][0] + (h * 256 + wave * 64) * 16),
          16, 0, 0);
    }
  };

  stage(0, 0);
  asm volatile("s_waitcnt vmcnt(0)" ::: "memory");
  __syncthreads();

  int cur = 0;
  const int NKT = KSLAB / 32;   // 16
  for (int kt = 0; kt < NKT; ++kt) {
    if (kt + 1 < NKT) stage(cur ^ 1, kt + 1);  // prefetch next tile
    short8 af[4], bfr[4];
#pragma unroll
    for (int m = 0; m < 4; ++m)
      af[m] = *(const short8*)&ldsA[cur][(wm * 64 + m * 16 + lr) * 32 + lk * 8];
#pragma unroll
    for (int n = 0; n < 4; ++n)
      bfr[n] = *(const short8*)&ldsB[cur][(wn * 64 + n * 16 + lr) * 32 + lk * 8];
#pragma unroll
    for (int m = 0; m < 4; ++m)
#pragma unroll
      for (int n = 0; n < 4; ++n)
        acc[m][n] = __builtin_amdgcn_mfma_f32_16x16x32_bf16(af[m], bfr[n], acc[m][n], 0, 0, 0);
    __syncthreads();  // drains vmcnt(0)+lgkmcnt(0): prefetch landed, reads done
    cur ^= 1;
  }

  // epilogue: C += LR * acc   (C/D layout: col=lane&15, row=(lane>>4)*4+r)
#pragma unroll
  for (int m = 0; m < 4; ++m)
#pragma unroll
    for (int n = 0; n < 4; ++n) {
      int col = j0 + wn * 64 + n * 16 + lr;
#pragma unroll
      for (int r = 0; r < 4; ++r) {
        int row = i0 + wm * 64 + m * 16 + lk * 4 + r;
        atomicAdd(&C[(size_t)row * NFEAT + col], LR * acc[m][n][r]);
      }
    }
}

extern "C" void kernel_launch(void* const* d_in, const int* in_sizes, int n_in,
                              void* d_out, int out_size, void* d_ws, size_t ws_size,
                              hipStream_t stream) {
  const float* weight  = (const float*)d_in[0];
  const float* in_spk  = (const float*)d_in[1];
  const float* out_spk = (const float*)d_in[2];
  float* out = (float*)d_out;

  u16* kinT = (u16*)d_ws;                                   // 8 MB bf16 [I][T]
  u16* outT = (u16*)d_ws + (size_t)T_STEPS * NFEAT;         // 8 MB bf16 [O][T]

  prep_kernel<<<dim3(1792), 256, 0, stream>>>(in_spk, out_spk, weight, kinT, outT, out);

  dim3 g3(NFEAT / 128, NFEAT / 128, SPLITK);
  stdp_gemm_kernel<<<g3, 256, 0, stream>>>(outT, kinT, out);
}

// Round 3
// 60.211 us; speedup vs baseline: 1.6422x; 1.6422x over previous
//
#include <hip/hip_runtime.h>
#include <cstdint>

#define T_STEPS 2048
#define NFEAT   2048
#define A_POS 0.05f
#define A_NEG 0.05f
#define LR    0.01f
#define DECAY 0.60653065971263342f   // exp(-1/2), tau_pos == tau_neg == 2

typedef unsigned short u16;
typedef short short8 __attribute__((ext_vector_type(8)));
typedef float f32x4 __attribute__((ext_vector_type(4)));

#define AS1 __attribute__((address_space(1)))
#define AS3 __attribute__((address_space(3)))

__device__ __forceinline__ uint32_t f2bf(float f) {
  uint32_t u = __float_as_uint(f);
  return (u + 0x7FFFu + ((u >> 16) & 1u)) >> 16;   // RNE, finite values only
}
__device__ __forceinline__ uint32_t packbf2(float lo, float hi) {
  return f2bf(lo) | (f2bf(hi) << 16);
}

// ---------------------------------------------------------------------------
// Prep kernel (fused, block-range dispatch):
//  blocks [0,256):     scan -> kinT[j][t] bf16    (exponential STDP scans)
//  blocks [256,1280):  transpose -> outT[i][t] bf16
// ---------------------------------------------------------------------------
#define TC   64
#define HALO 64
__global__ __launch_bounds__(256) void prep_kernel(
    const float* __restrict__ in, const float* __restrict__ outspk,
    u16* __restrict__ kinT, u16* __restrict__ outT) {
  const int bx = blockIdx.x;
  const int tid = threadIdx.x;

  if (bx < 256) {
    // ---- scan role ----
    const int j  = (bx & 7) * 256 + tid;
    const int t0 = (bx >> 3) * TC;
    const float d = DECAY;

    float kv[TC];
    float f = 0.f;
    int tb = t0 - HALO; if (tb < 0) tb = 0;
    for (int t = tb; t < t0; ++t) f = d * (f + in[(size_t)t * NFEAT + j]);
#pragma unroll
    for (int u = 0; u < TC; ++u) {
      kv[u] = f;                                   // F[t0+u] (excludes in[t0+u])
      f = d * (f + in[(size_t)(t0 + u) * NFEAT + j]);
    }

    float b = 0.f;
    int te = t0 + TC - 1 + HALO; if (te > T_STEPS - 1) te = T_STEPS - 1;
    for (int t = te; t >= t0 + TC; --t) b = in[(size_t)t * NFEAT + j] + d * b;
#pragma unroll
    for (int u = TC - 1; u >= 0; --u) {
      b = in[(size_t)(t0 + u) * NFEAT + j] + d * b;  // B[t0+u] (includes t)
      kv[u] = A_POS * kv[u] - A_NEG * b;
    }

    uint4* dst = (uint4*)&kinT[(size_t)j * T_STEPS + t0];
#pragma unroll
    for (int g = 0; g < TC / 8; ++g) {
      uint4 w;
      w.x = packbf2(kv[8 * g + 0], kv[8 * g + 1]);
      w.y = packbf2(kv[8 * g + 2], kv[8 * g + 3]);
      w.z = packbf2(kv[8 * g + 4], kv[8 * g + 5]);
      w.w = packbf2(kv[8 * g + 6], kv[8 * g + 7]);
      dst[g] = w;
    }
  } else {
    // ---- transpose role ----
    __shared__ float tile[64][65];
    const int b  = bx - 256;
    const int t0 = (b & 31) * 64;
    const int i0 = (b >> 5) * 64;
#pragma unroll
    for (int p = 0; p < 16; ++p) {
      int idx = tid + p * 256;
      int r = idx >> 6, c = idx & 63;
      tile[r][c] = outspk[(size_t)(t0 + r) * NFEAT + i0 + c];
    }
    __syncthreads();
#pragma unroll
    for (int p = 0; p < 8; ++p) {
      int idx = tid + p * 256;
      int pr = idx >> 5, pc = idx & 31;
      uint32_t w = packbf2(tile[2 * pc][pr], tile[2 * pc + 1][pr]);
      ((uint32_t*)outT)[(size_t)(i0 + pr) * (T_STEPS / 2) + (t0 >> 1) + pc] = w;
    }
  }
}

// ---------------------------------------------------------------------------
// GEMM: C[i][j] = W[i][j] + LR * sum_k A[i][k]*B[j][k]
// A = outT [2048][2048] bf16, B = kinT [2048][2048] bf16 (K-contiguous).
// Tile 128(M) x 64(N), BK=64, 4 waves (2x2, wave-tile 64x32), 512 blocks.
// T2 XOR-swizzled LDS (rule #21: inverse-swizzled global src + swizzled read).
// ---------------------------------------------------------------------------
__global__ __launch_bounds__(256) void stdp_gemm_kernel(
    const u16* __restrict__ A, const u16* __restrict__ B,
    const float* __restrict__ W, float* __restrict__ C) {
  __shared__ u16 ldsA[2][128 * 64];
  __shared__ u16 ldsB[2][64 * 64];
  const int tid = threadIdx.x;
  const int lane = tid & 63, wave = tid >> 6;
  const int wm = wave >> 1, wn = wave & 1;
  const int lr = lane & 15, lk = lane >> 4;

  // XCD-aware 8x8 chunked swizzle: grid 16(it) x 32(jt) = 512 blocks, 8 XCDs,
  // each XCD gets one 8x8 (it x jt) chunk pattern -> chunk grid is 2 x 4.
  const int bid = blockIdx.x;
  const int xcd = bid & 7, q = bid >> 3;          // q in [0,64)
  const int cit = xcd >> 2, cjt = xcd & 3;        // chunk coords 2 x 4
  const int it = cit * 8 + (q >> 3);
  const int jt = cjt * 8 + (q & 7);
  const int i0 = it * 128, j0 = jt * 64;

  f32x4 acc[4][2];
#pragma unroll
  for (int m = 0; m < 4; ++m)
#pragma unroll
    for (int n = 0; n < 2; ++n) acc[m][n] = (f32x4){0.f, 0.f, 0.f, 0.f};

  auto stage = [&](int buf, int kt) {
    const int k0 = kt * 64;
    // A-tile: 128 rows x 8 groups(16B) = 1024 chunks
#pragma unroll
    for (int p = 0; p < 4; ++p) {
      int ch = p * 256 + tid;
      int r = ch >> 3, c = ch & 7;
      int csw = c ^ (r & 7);                      // inverse-swizzle the SOURCE
      __builtin_amdgcn_global_load_lds(
          (const AS1 void*)(A + (size_t)(i0 + r) * T_STEPS + k0 + csw * 8),
          (AS3 void*)((char*)&ldsA[buf][0] + (p * 256 + wave * 64) * 16),
          16, 0, 0);
    }
    // B-tile: 64 rows x 8 groups = 512 chunks
#pragma unroll
    for (int p = 0; p < 2; ++p) {
      int ch = p * 256 + tid;
      int r = ch >> 3, c = ch & 7;
      int csw = c ^ (r & 7);
      __builtin_amdgcn_global_load_lds(
          (const AS1 void*)(B + (size_t)(j0 + r) * T_STEPS + k0 + csw * 8),
          (AS3 void*)((char*)&ldsB[buf][0] + (p * 256 + wave * 64) * 16),
          16, 0, 0);
    }
  };

  stage(0, 0);
  asm volatile("s_waitcnt vmcnt(0)" ::: "memory");
  __syncthreads();

  int cur = 0;
  const int NKT = T_STEPS / 64;   // 32
  for (int kt = 0; kt < NKT; ++kt) {
    if (kt + 1 < NKT) stage(cur ^ 1, kt + 1);  // prefetch next tile
#pragma unroll
    for (int ks = 0; ks < 2; ++ks) {
      short8 af[4], bf2[2];
#pragma unroll
      for (int m = 0; m < 4; ++m) {
        int row = wm * 64 + m * 16 + lr;
        int g = (ks * 4 + lk) ^ (row & 7);       // swizzled read
        af[m] = *(const short8*)((const char*)&ldsA[cur][0] + row * 128 + g * 16);
      }
#pragma unroll
      for (int n = 0; n < 2; ++n) {
        int row = wn * 32 + n * 16 + lr;
        int g = (ks * 4 + lk) ^ (row & 7);
        bf2[n] = *(const short8*)((const char*)&ldsB[cur][0] + row * 128 + g * 16);
      }
#pragma unroll
      for (int m = 0; m < 4; ++m)
#pragma unroll
        for (int n = 0; n < 2; ++n)
          acc[m][n] = __builtin_amdgcn_mfma_f32_16x16x32_bf16(af[m], bf2[n], acc[m][n], 0, 0, 0);
    }
    __syncthreads();  // drains vmcnt(0)+lgkmcnt(0): prefetch landed, reads done
    cur ^= 1;
  }

  // epilogue: C = W + LR * acc   (C/D layout: col=lane&15, row=(lane>>4)*4+r)
#pragma unroll
  for (int m = 0; m < 4; ++m)
#pragma unroll
    for (int n = 0; n < 2; ++n) {
      int col = j0 + wn * 32 + n * 16 + lr;
#pragma unroll
      for (int r = 0; r < 4; ++r) {
        int row = i0 + wm * 64 + m * 16 + lk * 4 + r;
        size_t off = (size_t)row * NFEAT + col;
        C[off] = W[off] + LR * acc[m][n][r];
      }
    }
}

extern "C" void kernel_launch(void* const* d_in, const int* in_sizes, int n_in,
                              void* d_out, int out_size, void* d_ws, size_t ws_size,
                              hipStream_t stream) {
  const float* weight  = (const float*)d_in[0];
  const float* in_spk  = (const float*)d_in[1];
  const float* out_spk = (const float*)d_in[2];
  float* out = (float*)d_out;

  u16* kinT = (u16*)d_ws;                                   // 8 MB bf16 [I][T]
  u16* outT = (u16*)d_ws + (size_t)T_STEPS * NFEAT;         // 8 MB bf16 [O][T]

  prep_kernel<<<dim3(1280), 256, 0, stream>>>(in_spk, out_spk, kinT, outT);

  stdp_gemm_kernel<<<dim3(512), 256, 0, stream>>>(outT, kinT, weight, out);
}